// Round 2
// 410.752 us; speedup vs baseline: 1.3003x; 1.3003x over previous
//
#include <hip/hip_runtime.h>

// GRU cell, B=32768, I=H=512, fp32 in/out, bf16 MFMA internals.
// R5 == R4 resubmitted (R4 bench died to a container-acquire infra error,
// no kernel verdict). Depth-3 prefetch pipeline (4 LDS buffers, counted
// vmcnt(12) steady state — loads span 3 K-steps instead of 1), pad removed
// (LDT 40->32) with XOR bank-swizzle baked into the global tile format
// (prep writes swizzled, global_load_lds stays linear, ds_read applies the
// same XOR). Numerics identical to R3 (same rounding points).
//
// ws layout (bytes):
//   [0,          2097152)   Wzr_t : bf16 B-tiles pass1, 32kt x 8nt x (128x32)
//   [2097152,    3145728)   Whh_t : bf16 B-tiles pass2, 32kt x 4nt x (128x32)
//   [3145728,   70254592)   XHt   : bf16 A-tiles [x|h], 256mt x 32kt x (128x32)
//   [70254592, 103809024)   HRt   : bf16 A-tiles h*r,   256mt x 16kt x (128x32)
//   [103809024,137363456)   Z     : z gate bf16 [32768][512]

#define BATCH 32768
#define HD 512
#define TS 4096                    // tile shorts: 128 rows x 32 k (8192 B)
#define STAGE_SHORTS (2 * TS)      // [B tile | A tile] = 16384 B
#define NBUF 4

typedef __attribute__((ext_vector_type(8))) short short8v;
typedef __attribute__((ext_vector_type(4))) float float4v;

typedef __attribute__((address_space(1))) unsigned int gu32_t;
typedef __attribute__((address_space(3))) unsigned int lu32_t;

__device__ __forceinline__ unsigned short f2bf(float f) {
  unsigned u = __float_as_uint(f);
  u += 0x7fffu + ((u >> 16) & 1u);   // round-to-nearest-even
  return (unsigned short)(u >> 16);
}
__device__ __forceinline__ float bf2f(unsigned short s) {
  return __uint_as_float(((unsigned)s) << 16);
}

// async 16B/lane global->LDS DMA. g is per-lane address, l is wave-uniform.
__device__ __forceinline__ void async_cp16(const void* g, void* l) {
  __builtin_amdgcn_global_load_lds(
      (gu32_t*)(unsigned long long)g,
      (lu32_t*)(unsigned int)(unsigned long long)l,
      16, 0, 0);
}

__device__ __forceinline__ float fast_sigmoid(float v) {
  return 1.0f / (1.0f + __expf(-v));
}
__device__ __forceinline__ float fast_tanh(float v) {
  float e = __expf(2.0f * v);
  return 1.0f - 2.0f / (e + 1.0f);
}

// swizzled short-index of element (r, c) within a 128x32 tile.
// XOR of bits 3..5 with row&7: consecutive-8-lane ds_read_b128 groups hit all
// 8 bank quads. Bijective; write (prep) and read (mfma) use the same map.
__device__ __forceinline__ int swz_idx(int r, int c) {
  return ((r << 5) + c) ^ ((r & 7) << 3);
}

// ---------------------------------------------------------------------------
// prep_all: blocks [0,8192) convert x,h -> XHt bf16 A-tiles (coalesced);
//           blocks [8192,14336) scatter fp32 weights -> bf16 B-tiles.
// ---------------------------------------------------------------------------
__global__ __launch_bounds__(256) void prep_all(
    const float* __restrict__ x, const float* __restrict__ h,
    const float* __restrict__ Wz, const float* __restrict__ Wr,
    const float* __restrict__ Uz, const float* __restrict__ Ur,
    const float* __restrict__ Wh, const float* __restrict__ Uh,
    unsigned short* __restrict__ XHt,
    unsigned short* __restrict__ Wzr_t, unsigned short* __restrict__ Whh_t) {
  int b = blockIdx.x;
  int t = threadIdx.x;
  if (b < 8192) {
    // conv: one 128x32 tile per block, coalesced float4 reads.
    int kt = b & 31, mt = b >> 5;
    const float* src = (kt < 16)
        ? (x + (size_t)(mt * 128) * HD + kt * 32)
        : (h + (size_t)(mt * 128) * HD + (kt - 16) * 32);
    unsigned short* dst = XHt + (size_t)b * TS;
    int r0 = t >> 3, c0 = (t & 7) * 4;
#pragma unroll
    for (int it = 0; it < 4; ++it) {
      int r = r0 + it * 32;
      float4 v = *(const float4*)(src + (size_t)r * HD + c0);
      short4 s;
      s.x = (short)f2bf(v.x); s.y = (short)f2bf(v.y);
      s.z = (short)f2bf(v.z); s.w = (short)f2bf(v.w);
      // swizzle flips bits >=3 only: 4-short granule stays intact
      *(short4*)(dst + swz_idx(r, c0)) = s;
    }
  } else {
    int e = (b - 8192) * 256 + t;
    if (e < 256 * TS) {
      // Wzr: 32kt x 8nt tiles; rows n (output col), cols k
      int tile = e >> 12, rem = e & 4095;
      int r = rem >> 5, c = rem & 31;
      int kt = tile >> 3, nt = tile & 7;
      int n = nt * 128 + r;       // 0..1023
      int k = kt * 32 + c;        // 0..1023
      int nn = (n < 512) ? n : (n - 512);
      float v;
      if (k < 512) v = (n < 512) ? Wz[nn * 512 + k] : Wr[nn * 512 + k];
      else         v = (n < 512) ? Uz[nn * 512 + (k - 512)] : Ur[nn * 512 + (k - 512)];
      Wzr_t[(tile << 12) + (rem ^ ((r & 7) << 3))] = f2bf(v);
    } else {
      int e2 = e - 256 * TS;
      if (e2 < 128 * TS) {
        int tile = e2 >> 12, rem = e2 & 4095;
        int r = rem >> 5, c = rem & 31;
        int kt = tile >> 2, nt = tile & 3;
        int n = nt * 128 + r;     // 0..511
        int k = kt * 32 + c;      // 0..1023
        float v = (k < 512) ? Wh[n * 512 + k] : Uh[n * 512 + (k - 512)];
        Whh_t[(tile << 12) + (rem ^ ((r & 7) << 3))] = f2bf(v);
      }
    }
  }
}

// ---------------------------------------------------------------------------
// staging: stage = [B tile (8192 B) | A tile (8192 B)], each wave issues
// exactly 4 x 1KB DMAs: waves 0-1 cover B, waves 2-3 cover A.
// ---------------------------------------------------------------------------
__device__ __forceinline__ void prefetch_pair(const unsigned short* __restrict__ Bt,
                                              const unsigned short* __restrict__ At,
                                              unsigned short* stage,
                                              int wave, int lane) {
  const char* gb = (wave < 2) ? ((const char*)Bt + wave * 4096)
                              : ((const char*)At + (wave - 2) * 4096);
  char* lb = (char*)stage + wave * 4096;
#pragma unroll
  for (int i = 0; i < 4; ++i)
    async_cp16(gb + i * 1024 + lane * 16, lb + i * 1024);
}

__device__ __forceinline__ void mfma_step(const unsigned short* stage,
                                          float4v acc[4][4],
                                          int wm, int wn, int quad, int l16) {
  const unsigned short* Blds = stage;        // B tile at offset 0
  const unsigned short* Alds = stage + TS;   // A tile at +8192 B
  const int sw = (l16 & 7) << 3;             // row&7 == l16&7 (wm,i*16 mult of 16)
  short8v a[4], b[4];
#pragma unroll
  for (int i = 0; i < 4; ++i) {
    int r = wm + i * 16 + l16;
    a[i] = *(const short8v*)(Alds + (((r << 5) + (quad << 3)) ^ sw));
  }
#pragma unroll
  for (int j = 0; j < 4; ++j) {
    int r = wn + j * 16 + l16;
    b[j] = *(const short8v*)(Blds + (((r << 5) + (quad << 3)) ^ sw));
  }
#pragma unroll
  for (int i = 0; i < 4; ++i)
#pragma unroll
    for (int j = 0; j < 4; ++j)
      acc[i][j] = __builtin_amdgcn_mfma_f32_16x16x32_bf16(a[i], b[j], acc[i][j], 0, 0, 0);
}

// each wave issues exactly 4 loads per staged tile; depth-3 pipeline =>
// steady-state wait is vmcnt(12) (3 batches in flight), tail 8/4/0.
#define WAIT_VM12() asm volatile("s_waitcnt vmcnt(12)" ::: "memory")
#define WAIT_VM8()  asm volatile("s_waitcnt vmcnt(8)" ::: "memory")
#define WAIT_VM4()  asm volatile("s_waitcnt vmcnt(4)" ::: "memory")
#define WAIT_VM0()  asm volatile("s_waitcnt vmcnt(0)" ::: "memory")
#define RAW_BAR()   asm volatile("s_barrier" ::: "memory")

// ---------------------------------------------------------------------------
// pass 1: pre_zr = [x|h] @ B1 ; z = sigmoid -> Z ; r -> HRt = bf16(h*r)
// grid 2048 linear; swizzle: xcd=b&7, q=b>>3, nt=q&7, mt=(b&7)*32+(q>>3)
// ---------------------------------------------------------------------------
__global__ __launch_bounds__(256, 2) void gemm_zr(
    const float* __restrict__ h,
    const unsigned short* __restrict__ XHt,
    const unsigned short* __restrict__ Wt,
    const float* __restrict__ Wz_b, const float* __restrict__ Uz_b,
    const float* __restrict__ Wr_b, const float* __restrict__ Ur_b,
    unsigned short* __restrict__ Z, unsigned short* __restrict__ HRt) {
  __shared__ __align__(16) unsigned short Stg[NBUF][STAGE_SHORTS];
  const int tid = threadIdx.x;
  const int wave = tid >> 6, lane = tid & 63;
  const int quad = lane >> 4, l16 = lane & 15;
  const int b = blockIdx.x;
  const int q = b >> 3;
  const int nt = q & 7;                   // 0..7
  const int mt = (b & 7) * 32 + (q >> 3); // 0..255
  const int m0 = mt * 128;
  const int wm = (wave >> 1) * 64, wn = (wave & 1) * 64;

  float4v acc[4][4] = {};

  const unsigned short* Abase = XHt + (size_t)(mt * 32) * TS;
#pragma unroll
  for (int p = 0; p < 3; ++p)
    prefetch_pair(Wt + (size_t)(p * 8 + nt) * TS, Abase + (size_t)p * TS,
                  Stg[p], wave, lane);
  for (int kt = 0; kt < 32; ++kt) {
    if (kt <= 28) {
      prefetch_pair(Wt + (size_t)((kt + 3) * 8 + nt) * TS,
                    Abase + (size_t)(kt + 3) * TS,
                    Stg[(kt + 3) & 3], wave, lane);
      WAIT_VM12();
    } else if (kt == 29) {
      WAIT_VM8();
    } else if (kt == 30) {
      WAIT_VM4();
    } else {
      WAIT_VM0();
    }
    RAW_BAR();
    mfma_step(Stg[kt & 3], acc, wm, wn, quad, l16);
    RAW_BAR();
  }

  const int n0 = nt * 128;
  if (n0 < 512) {
    // z gate
#pragma unroll
    for (int j = 0; j < 4; ++j) {
      int n = n0 + wn + j * 16 + l16;
      float bias = Wz_b[n] + Uz_b[n];
#pragma unroll
      for (int i = 0; i < 4; ++i) {
#pragma unroll
        for (int reg = 0; reg < 4; ++reg) {
          int m = m0 + wm + i * 16 + quad * 4 + reg;
          float v = fast_sigmoid(acc[i][j][reg] + bias);
          Z[(size_t)m * HD + n] = f2bf(v);
        }
      }
    }
  } else {
    // r gate -> hr = h*r, stored pre-tiled (swizzled) as pass-2 A tiles
#pragma unroll
    for (int j = 0; j < 4; ++j) {
      int nn = (n0 - 512) + wn + j * 16 + l16;   // 0..511
      float bias = Wr_b[nn] + Ur_b[nn];
      int ktile = nn >> 5, kc = nn & 31;
#pragma unroll
      for (int i = 0; i < 4; ++i) {
#pragma unroll
        for (int reg = 0; reg < 4; ++reg) {
          int m = m0 + wm + i * 16 + quad * 4 + reg;
          float rv = fast_sigmoid(acc[i][j][reg] + bias);
          float hv = h[(size_t)m * HD + nn];
          int mr = m & 127;
          HRt[(size_t)(mt * 16 + ktile) * TS + swz_idx(mr, kc)] = f2bf(hv * rv);
        }
      }
    }
  }
}

// ---------------------------------------------------------------------------
// pass 2: pre_h = [x|hr] @ B2 ; ht = tanh ; h_next = h + z*(ht - h) -> out x2
// grid 1024 linear; swizzle: xcd=b&7, q=b>>3, nt=q&3, mt=(b&7)*32+(q>>2)
// ---------------------------------------------------------------------------
__global__ __launch_bounds__(256, 2) void gemm_out(
    const float* __restrict__ h,
    const unsigned short* __restrict__ XHt,
    const unsigned short* __restrict__ Wt,
    const float* __restrict__ Wh_b, const float* __restrict__ Uh_b,
    const unsigned short* __restrict__ Z, const unsigned short* __restrict__ HRt,
    float* __restrict__ out) {
  __shared__ __align__(16) unsigned short Stg[NBUF][STAGE_SHORTS];
  const int tid = threadIdx.x;
  const int wave = tid >> 6, lane = tid & 63;
  const int quad = lane >> 4, l16 = lane & 15;
  const int b = blockIdx.x;
  const int q = b >> 3;
  const int nt = q & 3;                   // 0..3
  const int mt = (b & 7) * 32 + (q >> 2); // 0..255
  const int m0 = mt * 128;
  const int wm = (wave >> 1) * 64, wn = (wave & 1) * 64;

  float4v acc[4][4] = {};

  const unsigned short* Ax = XHt + (size_t)(mt * 32) * TS;  // kt 0..15 (x part)
  const unsigned short* Ah = HRt + (size_t)(mt * 16) * TS;  // kt 16..31 (hr part)
#pragma unroll
  for (int p = 0; p < 3; ++p)
    prefetch_pair(Wt + (size_t)(p * 4 + nt) * TS, Ax + (size_t)p * TS,
                  Stg[p], wave, lane);
  for (int kt = 0; kt < 32; ++kt) {
    if (kt <= 28) {
      int kn = kt + 3;
      const unsigned short* At = (kn < 16) ? (Ax + (size_t)kn * TS)
                                           : (Ah + (size_t)(kn - 16) * TS);
      prefetch_pair(Wt + (size_t)(kn * 4 + nt) * TS, At,
                    Stg[kn & 3], wave, lane);
      WAIT_VM12();
    } else if (kt == 29) {
      WAIT_VM8();
    } else if (kt == 30) {
      WAIT_VM4();
    } else {
      WAIT_VM0();
    }
    RAW_BAR();
    mfma_step(Stg[kt & 3], acc, wm, wn, quad, l16);
    RAW_BAR();
  }

  const int n0 = nt * 128;
#pragma unroll
  for (int j = 0; j < 4; ++j) {
    int n = n0 + wn + j * 16 + l16;
    float bias = Wh_b[n] + Uh_b[n];
#pragma unroll
    for (int i = 0; i < 4; ++i) {
#pragma unroll
      for (int reg = 0; reg < 4; ++reg) {
        int m = m0 + wm + i * 16 + quad * 4 + reg;
        size_t idx = (size_t)m * HD + n;
        float ht = fast_tanh(acc[i][j][reg] + bias);
        float hv = h[idx];
        float zv = bf2f(Z[idx]);
        float o = fmaf(zv, ht - hv, hv);
        out[idx] = o;
        out[(size_t)BATCH * HD + idx] = o;
      }
    }
  }
}

// ---------------------------------------------------------------------------
extern "C" void kernel_launch(void* const* d_in, const int* in_sizes, int n_in,
                              void* d_out, int out_size, void* d_ws, size_t ws_size,
                              hipStream_t stream) {
  const float* x    = (const float*)d_in[0];
  const float* h    = (const float*)d_in[1];
  const float* Wz_w = (const float*)d_in[2];
  const float* Wz_b = (const float*)d_in[3];
  const float* Wr_w = (const float*)d_in[4];
  const float* Wr_b = (const float*)d_in[5];
  const float* Wh_w = (const float*)d_in[6];
  const float* Wh_b = (const float*)d_in[7];
  const float* Uz_w = (const float*)d_in[8];
  const float* Uz_b = (const float*)d_in[9];
  const float* Ur_w = (const float*)d_in[10];
  const float* Ur_b = (const float*)d_in[11];
  const float* Uh_w = (const float*)d_in[12];
  const float* Uh_b = (const float*)d_in[13];
  float* out = (float*)d_out;

  char* ws = (char*)d_ws;
  unsigned short* Wzr_t = (unsigned short*)(ws);                //  2,097,152 B
  unsigned short* Whh_t = (unsigned short*)(ws + 2097152);      //  1,048,576 B
  unsigned short* XHt   = (unsigned short*)(ws + 3145728);      // 67,108,864 B
  unsigned short* HRt   = (unsigned short*)(ws + 70254592);     // 33,554,432 B
  unsigned short* Z     = (unsigned short*)(ws + 103809024);    // 33,554,432 B

  prep_all<<<14336, 256, 0, stream>>>(x, h, Wz_w, Wr_w, Uz_w, Ur_w, Wh_w, Uh_w,
                                      XHt, Wzr_t, Whh_t);
  gemm_zr<<<2048, 256, 0, stream>>>(h, XHt, Wzr_t, Wz_b, Uz_b, Wr_b, Ur_b, Z, HRt);
  gemm_out<<<1024, 256, 0, stream>>>(h, XHt, Whh_t, Wh_b, Uh_b, Z, HRt, out);
}